// Round 2
// baseline (226.048 us; speedup 1.0000x reference)
//
#include <hip/hip_runtime.h>
#include <hip/hip_fp16.h>

#define N_TOT 65536
#define D_DIM 512
#define K_DIM 64
#define NC    32          // n-rows per LDS chunk (one MFMA K=32 step)
#define HT_S  40          // LDS row stride in bf16 elems (32 data + 8 pad) = 80 B, 16B-aligned
#define GSZ   (K_DIM * D_DIM)   // 32768 elements of partial G

typedef __bf16   bf16x8 __attribute__((ext_vector_type(8)));
typedef float    f32x4  __attribute__((ext_vector_type(4)));
typedef _Float16 half8  __attribute__((ext_vector_type(8)));

__device__ __forceinline__ unsigned int pack_bf16(float a, float b) {
    union { float f; unsigned int u; } x, y;
    x.f = a; y.f = b;
    unsigned int lo = (x.u + 0x7fffu + ((x.u >> 16) & 1u)) >> 16;   // RNE
    unsigned int hi = (y.u + 0x7fffu + ((y.u >> 16) & 1u)) >> 16;
    return lo | (hi << 16);
}

// K1: per-block partial G = F_chunk^T * h_chunk (bf16 MFMA, fp32 acc -> fp16 store)
//     + per-block partial sum(h^2) in fp32.  Double-buffered LDS: one barrier
//     per chunk; chunk c+1's global loads overlap chunk c's MFMA.
extern "C" __global__ void __launch_bounds__(1024)
k1_partial(const float* __restrict__ h, const float* __restrict__ F,
           float* __restrict__ trw_out, unsigned short* __restrict__ gpart,
           float* __restrict__ out, int rowsPerBlock) {
    __shared__ unsigned short ht[2][D_DIM * HT_S];   // 2 x 40960 B, transposed h: ht[d][n]
    __shared__ unsigned short Ft[2][K_DIM * HT_S];   // 2 x  5120 B, transposed F: Ft[k][n]
    __shared__ float red[16];

    const int tid = threadIdx.x;
    const int b   = blockIdx.x;
    if (b == 0 && tid == 0) out[0] = 0.0f;        // d_out is poisoned; zero before K2

    const int row0    = b * rowsPerBlock;
    const int nChunks = rowsPerBlock / NC;

    // staging ids (h): float2 along d; thread = (d-pair, row-group)
    const int d2 = tid & 255;     // d-pair index: d = 2*d2, 2*d2+1
    const int rp = tid >> 8;      // 0..3 row-pair group
    // staging ids (F)
    const int fk = tid & 63;      // k
    const int fp = tid >> 6;      // 0..15 (row pair)
    // mfma ids
    const int wave = tid >> 6;    // 0..15 ; wave owns d in [32w, 32w+32)
    const int lane = tid & 63;
    const int m    = lane & 15;
    const int q    = lane >> 4;

    f32x4 acc[4][2];
    #pragma unroll
    for (int kt = 0; kt < 4; ++kt)
        #pragma unroll
        for (int dt = 0; dt < 2; ++dt)
            acc[kt][dt] = (f32x4){0.f, 0.f, 0.f, 0.f};

    float trw = 0.f;

    // ---- staging lambda: stage chunk c into buffer p ----
    auto stage = [&](int c, int p) {
        const int r0 = row0 + c * NC;
        const float2* hb = (const float2*)(h + (size_t)r0 * D_DIM);
        #pragma unroll
        for (int it = 0; it < 4; ++it) {
            const int r = it * 8 + rp * 2;        // even row in [0,32)
            float2 v0 = hb[(size_t)r       * 256 + d2];
            float2 v1 = hb[(size_t)(r + 1) * 256 + d2];
            trw += v0.x * v0.x + v0.y * v0.y + v1.x * v1.x + v1.y * v1.y;
            *(unsigned int*)&ht[p][(2 * d2)     * HT_S + r] = pack_bf16(v0.x, v1.x);
            *(unsigned int*)&ht[p][(2 * d2 + 1) * HT_S + r] = pack_bf16(v0.y, v1.y);
        }
        const float* fb = F + (size_t)r0 * K_DIM;
        const int r = fp * 2;
        float v0 = fb[(size_t)r       * K_DIM + fk];
        float v1 = fb[(size_t)(r + 1) * K_DIM + fk];
        *(unsigned int*)&Ft[p][fk * HT_S + r] = pack_bf16(v0, v1);
    };

    stage(0, 0);   // prologue

    for (int c = 0; c < nChunks; ++c) {
        __syncthreads();                          // buf[c&1] ready; buf[(c+1)&1] free
        if (c + 1 < nChunks) stage(c + 1, (c + 1) & 1);

        const int p = c & 1;
        bf16x8 bfrag[2], afrag[4];
        #pragma unroll
        for (int dt = 0; dt < 2; ++dt)
            bfrag[dt] = *(const bf16x8*)&ht[p][(wave * 32 + dt * 16 + m) * HT_S + q * 8];
        #pragma unroll
        for (int kt = 0; kt < 4; ++kt)
            afrag[kt] = *(const bf16x8*)&Ft[p][(kt * 16 + m) * HT_S + q * 8];
        #pragma unroll
        for (int kt = 0; kt < 4; ++kt)
            #pragma unroll
            for (int dt = 0; dt < 2; ++dt)
                acc[kt][dt] = __builtin_amdgcn_mfma_f32_16x16x32_bf16(
                    afrag[kt], bfrag[dt], acc[kt][dt], 0, 0, 0);
    }

    // ---- epilogue: partial G -> fp16 in workspace ----
    unsigned short* gp = gpart + (size_t)b * GSZ;
    #pragma unroll
    for (int kt = 0; kt < 4; ++kt)
        #pragma unroll
        for (int dt = 0; dt < 2; ++dt)
            #pragma unroll
            for (int r = 0; r < 4; ++r) {
                const int k = kt * 16 + q * 4 + r;      // C/D row = (lane>>4)*4 + reg
                const int d = wave * 32 + dt * 16 + m;  // C/D col = lane&15
                __half hv = __float2half(acc[kt][dt][r]);
                gp[k * D_DIM + d] = *(unsigned short*)&hv;
            }

    // ---- tr_wtw partial: wave shuffle reduce -> LDS -> one store ----
    #pragma unroll
    for (int off = 32; off > 0; off >>= 1) trw += __shfl_down(trw, off, 64);
    if (lane == 0) red[wave] = trw;
    __syncthreads();
    if (tid == 0) {
        float s = 0.f;
        #pragma unroll
        for (int w = 0; w < 16; ++w) s += red[w];
        trw_out[b] = s;
    }
}

// K2: out = sum_b trw[b] - sum_{k,d} (sum_b Gpart[b][k,d])^2
extern "C" __global__ void __launch_bounds__(1024)
k2_reduce(const float* __restrict__ trw, const unsigned short* __restrict__ gpart,
          float* __restrict__ out, int P) {
    __shared__ float sh[4 * 256 * 8];   // 32 KB: [sub][local][j]
    __shared__ float red[4];

    const int sub   = threadIdx.x >> 8;        // 0..3 : b-split
    const int local = threadIdx.x & 255;
    const int tt    = blockIdx.x * 256 + local; // 0..4095 ; elements 8tt..8tt+7

    float g[8];
    #pragma unroll
    for (int j = 0; j < 8; ++j) g[j] = 0.f;

    const unsigned short* base = gpart + (size_t)tt * 8;
    for (int b = sub; b < P; b += 4) {
        half8 v = *(const half8*)(base + (size_t)b * GSZ);
        #pragma unroll
        for (int j = 0; j < 8; ++j) g[j] += (float)v[j];
    }
    #pragma unroll
    for (int j = 0; j < 8; ++j) sh[(sub * 256 + local) * 8 + j] = g[j];
    __syncthreads();

    float s = 0.f;
    if (threadIdx.x < 256) {
        #pragma unroll
        for (int j = 0; j < 8; ++j) {
            float gg = sh[(0 * 256 + local) * 8 + j] + sh[(1 * 256 + local) * 8 + j]
                     + sh[(2 * 256 + local) * 8 + j] + sh[(3 * 256 + local) * 8 + j];
            s -= gg * gg;
        }
        if (tt < P) s += trw[tt];
        #pragma unroll
        for (int off = 32; off > 0; off >>= 1) s += __shfl_down(s, off, 64);
        if ((threadIdx.x & 63) == 0) red[threadIdx.x >> 6] = s;
    }
    __syncthreads();
    if (threadIdx.x == 0)
        atomicAdd(out, red[0] + red[1] + red[2] + red[3]);
}

extern "C" void kernel_launch(void* const* d_in, const int* in_sizes, int n_in,
                              void* d_out, int out_size, void* d_ws, size_t ws_size,
                              hipStream_t stream) {
    const float* h = (const float*)d_in[0];   // [65536, 512]
    const float* F = (const float*)d_in[1];   // [65536, 64]
    float* out = (float*)d_out;

    // ws layout: [0,4096): trw fp32 (P<=256) ; [4096, 4096+P*64KiB): fp16 partial G
    int P = 256;
    while (P > 1 && (size_t)4096 + (size_t)P * (GSZ * 2) > ws_size) P >>= 1;
    const int rowsPerBlock = N_TOT / P;

    float* trw = (float*)d_ws;
    unsigned short* gpart = (unsigned short*)((char*)d_ws + 4096);

    hipLaunchKernelGGL(k1_partial, dim3(P), dim3(1024), 0, stream,
                       h, F, trw, gpart, out, rowsPerBlock);
    hipLaunchKernelGGL(k2_reduce, dim3(16), dim3(1024), 0, stream,
                       trw, gpart, out, P);
}

// Round 3
// 210.928 us; speedup vs baseline: 1.0717x; 1.0717x over previous
//
#include <hip/hip_runtime.h>
#include <hip/hip_fp16.h>

#define N_TOT 65536
#define D_DIM 512
#define K_DIM 64
#define NC    32          // n-rows per LDS chunk (one MFMA K=32 step)
#define HT_S  40          // LDS row stride in bf16 elems = 80 B = 20 dwords (16B-aligned rows)
#define GSZ   (K_DIM * D_DIM)   // 32768 elements of partial G

typedef __bf16   bf16x8 __attribute__((ext_vector_type(8)));
typedef float    f32x4  __attribute__((ext_vector_type(4)));
typedef _Float16 half8  __attribute__((ext_vector_type(8)));

__device__ __forceinline__ unsigned int pack_bf16(float a, float b) {
    union { float f; unsigned int u; } x, y;
    x.f = a; y.f = b;
    unsigned int lo = (x.u + 0x7fffu + ((x.u >> 16) & 1u)) >> 16;   // RNE
    unsigned int hi = (y.u + 0x7fffu + ((y.u >> 16) & 1u)) >> 16;
    return lo | (hi << 16);
}

// K1: per-block partial G = F_chunk^T * h_chunk (bf16 MFMA, fp32 acc -> fp16 store)
//     + per-block partial sum(h^2).
// Staging: each lane packs 8 n-values of ONE d-row -> single ds_write_b128.
//   Start bank = (20*d + 4*g) % 32 over consecutive-d lanes -> 8-phase minimum,
//   i.e. conflict-free (vs 16-way conflicts of the packed-dword scatter in R2).
extern "C" __global__ void __launch_bounds__(1024)
k1_partial(const float* __restrict__ h, const float* __restrict__ F,
           float* __restrict__ trw_out, unsigned short* __restrict__ gpart,
           float* __restrict__ out, int rowsPerBlock) {
    __shared__ unsigned short ht[2][D_DIM * HT_S];   // 2 x 40960 B, ht[d][n]
    __shared__ unsigned short Ft[2][K_DIM * HT_S];   // 2 x  5120 B, Ft[k][n]
    __shared__ float red[16];

    const int tid = threadIdx.x;
    const int b   = blockIdx.x;
    if (b == 0 && tid == 0) out[0] = 0.0f;        // d_out is poisoned; zero before K2

    const int row0    = b * rowsPerBlock;
    const int nChunks = rowsPerBlock / NC;

    // staging ids (h): lane owns one d-row; sg picks 2 of the 4 8-row groups
    const int sd = tid & 511;     // d
    const int sg = tid >> 9;      // 0..1
    // staging ids (F): threads 0..255 only
    const int fk = tid & 63;      // k
    const int fg = (tid >> 6) & 3;// 8-row group
    // mfma ids
    const int wave = tid >> 6;    // 0..15 ; wave owns d in [32w, 32w+32)
    const int lane = tid & 63;
    const int m    = lane & 15;
    const int q    = lane >> 4;

    f32x4 acc[4][2];
    #pragma unroll
    for (int kt = 0; kt < 4; ++kt)
        #pragma unroll
        for (int dt = 0; dt < 2; ++dt)
            acc[kt][dt] = (f32x4){0.f, 0.f, 0.f, 0.f};

    float trw = 0.f;

    auto stage = [&](int c, int p) {
        const int r0 = row0 + c * NC;
        const float* hb = h + (size_t)r0 * D_DIM + sd;
        #pragma unroll
        for (int gi = 0; gi < 2; ++gi) {
            const int g8 = gi * 2 + sg;           // 8-row group 0..3
            float v[8];
            #pragma unroll
            for (int j = 0; j < 8; ++j) {
                v[j] = hb[(size_t)(g8 * 8 + j) * D_DIM];
                trw += v[j] * v[j];
            }
            uint4 pk;
            pk.x = pack_bf16(v[0], v[1]);
            pk.y = pack_bf16(v[2], v[3]);
            pk.z = pack_bf16(v[4], v[5]);
            pk.w = pack_bf16(v[6], v[7]);
            *(uint4*)&ht[p][sd * HT_S + g8 * 8] = pk;   // byte 80*sd+16*g8: 16B-aligned
        }
        if (tid < 256) {
            const float* fb = F + (size_t)r0 * K_DIM + fk;
            float w[8];
            #pragma unroll
            for (int j = 0; j < 8; ++j)
                w[j] = fb[(size_t)(fg * 8 + j) * K_DIM];
            uint4 pk;
            pk.x = pack_bf16(w[0], w[1]);
            pk.y = pack_bf16(w[2], w[3]);
            pk.z = pack_bf16(w[4], w[5]);
            pk.w = pack_bf16(w[6], w[7]);
            *(uint4*)&Ft[p][fk * HT_S + fg * 8] = pk;
        }
    };

    stage(0, 0);   // prologue

    for (int c = 0; c < nChunks; ++c) {
        __syncthreads();                          // buf[c&1] ready; other buf free
        if (c + 1 < nChunks) stage(c + 1, (c + 1) & 1);

        const int p = c & 1;
        bf16x8 bfrag[2], afrag[4];
        #pragma unroll
        for (int dt = 0; dt < 2; ++dt)
            bfrag[dt] = *(const bf16x8*)&ht[p][(wave * 32 + dt * 16 + m) * HT_S + q * 8];
        #pragma unroll
        for (int kt = 0; kt < 4; ++kt)
            afrag[kt] = *(const bf16x8*)&Ft[p][(kt * 16 + m) * HT_S + q * 8];
        #pragma unroll
        for (int kt = 0; kt < 4; ++kt)
            #pragma unroll
            for (int dt = 0; dt < 2; ++dt)
                acc[kt][dt] = __builtin_amdgcn_mfma_f32_16x16x32_bf16(
                    afrag[kt], bfrag[dt], acc[kt][dt], 0, 0, 0);
    }

    // ---- epilogue: partial G -> fp16 in workspace ----
    unsigned short* gp = gpart + (size_t)b * GSZ;
    #pragma unroll
    for (int kt = 0; kt < 4; ++kt)
        #pragma unroll
        for (int dt = 0; dt < 2; ++dt)
            #pragma unroll
            for (int r = 0; r < 4; ++r) {
                const int k = kt * 16 + q * 4 + r;      // C/D row = (lane>>4)*4 + reg
                const int d = wave * 32 + dt * 16 + m;  // C/D col = lane&15
                __half hv = __float2half(acc[kt][dt][r]);
                gp[k * D_DIM + d] = *(unsigned short*)&hv;
            }

    // ---- tr_wtw partial: wave shuffle reduce -> LDS -> one store ----
    #pragma unroll
    for (int off = 32; off > 0; off >>= 1) trw += __shfl_down(trw, off, 64);
    if (lane == 0) red[wave] = trw;
    __syncthreads();
    if (tid == 0) {
        float s = 0.f;
        #pragma unroll
        for (int w = 0; w < 16; ++w) s += red[w];
        trw_out[b] = s;
    }
}

// K2: out = sum_b trw[b] - sum_{k,d} (sum_b Gpart[b][k,d])^2
// 256 blocks (R2 used 16 blocks = 16 CUs -> per-CU BW bound ~35 µs).
extern "C" __global__ void __launch_bounds__(512)
k2_reduce(const float* __restrict__ trw, const unsigned short* __restrict__ gpart,
          float* __restrict__ out, int P) {
    __shared__ float sh[32 * 16 * 8];   // 16 KB: [sub][oct][j]
    __shared__ float red2[8];

    const int tid = threadIdx.x;
    const int sub = tid >> 4;                  // 0..31 : b-split
    const int oct = tid & 15;
    const int tt  = blockIdx.x * 16 + oct;     // 0..4095 ; elements 8tt..8tt+7

    float g[8];
    #pragma unroll
    for (int j = 0; j < 8; ++j) g[j] = 0.f;

    const unsigned short* base = gpart + (size_t)tt * 8;
    for (int b = sub; b < P; b += 32) {
        half8 v = *(const half8*)(base + (size_t)b * GSZ);
        #pragma unroll
        for (int j = 0; j < 8; ++j) g[j] += (float)v[j];
    }
    #pragma unroll
    for (int j = 0; j < 8; ++j) sh[(sub * 16 + oct) * 8 + j] = g[j];
    __syncthreads();

    float val = 0.f;
    if (tid < 128) {
        const int o2 = tid >> 3, j = tid & 7;
        float s = 0.f;
        #pragma unroll
        for (int sb = 0; sb < 32; ++sb) s += sh[(sb * 16 + o2) * 8 + j];
        val = -s * s;
    } else if (blockIdx.x == 0 && tid - 128 < P) {
        val = trw[tid - 128];                  // fold tr_wtw partials in block 0
    }

    #pragma unroll
    for (int off = 32; off > 0; off >>= 1) val += __shfl_down(val, off, 64);
    if ((tid & 63) == 0) red2[tid >> 6] = val;
    __syncthreads();
    if (tid == 0) {
        float s = 0.f;
        #pragma unroll
        for (int w = 0; w < 8; ++w) s += red2[w];
        atomicAdd(out, s);
    }
}

extern "C" void kernel_launch(void* const* d_in, const int* in_sizes, int n_in,
                              void* d_out, int out_size, void* d_ws, size_t ws_size,
                              hipStream_t stream) {
    const float* h = (const float*)d_in[0];   // [65536, 512]
    const float* F = (const float*)d_in[1];   // [65536, 64]
    float* out = (float*)d_out;

    // ws layout: [0,4096): trw fp32 (P<=256) ; [4096, 4096+P*64KiB): fp16 partial G
    int P = 256;
    while (P > 1 && (size_t)4096 + (size_t)P * (GSZ * 2) > ws_size) P >>= 1;
    const int rowsPerBlock = N_TOT / P;

    float* trw = (float*)d_ws;
    unsigned short* gpart = (unsigned short*)((char*)d_ws + 4096);

    hipLaunchKernelGGL(k1_partial, dim3(P), dim3(1024), 0, stream,
                       h, F, trw, gpart, out, rowsPerBlock);
    hipLaunchKernelGGL(k2_reduce, dim3(256), dim3(512), 0, stream,
                       trw, gpart, out, P);
}